// Round 12
// baseline (294.265 us; speedup 1.0000x reference)
//
#include <hip/hip_runtime.h>

#define NN 8192
#define CC 64

typedef float f32x4 __attribute__((ext_vector_type(4)));
typedef short short8 __attribute__((ext_vector_type(8)));
typedef unsigned short u16x4 __attribute__((ext_vector_type(4)));

__device__ __forceinline__ unsigned short f2bf(float f) {
    union { float f; unsigned u; } v; v.f = f;
    return (unsigned short)((v.u + 0x7fffu + ((v.u >> 16) & 1u)) >> 16);
}
__device__ __forceinline__ float b2f(unsigned short h) {
    union { unsigned u; float f; } v; v.u = ((unsigned)h) << 16;
    return v.f;
}

// labT[c][k] = bf16(labels[k][c]); grid 512 x 256
__global__ __launch_bounds__(256)
void prep_labels(const float* __restrict__ labels, unsigned short* __restrict__ labT) {
    const int gid = blockIdx.x * 256 + threadIdx.x;   // 0 .. 131071
    const int k  = gid >> 4;
    const int c4 = (gid & 15) << 2;
    f32x4 v = *(const f32x4*)(labels + (size_t)k * CC + c4);
#pragma unroll
    for (int j = 0; j < 4; ++j)
        labT[(size_t)(c4 + j) * NN + k] = f2bf(v[j]);
}

// ---------------- K1: streaming normalize -> P only ----------------
// One row per 256-thread block. Read b,m (nt); f32 products in regs;
// row L1 sum; P = bf16(p*scale) (plain store -> L3 for K2). NO T store.
__global__ __launch_bounds__(256)
void lp_stream(const float* __restrict__ bi, const float* __restrict__ mk,
               unsigned short* __restrict__ P)
{
    __shared__ float scr[4];
    const int t    = threadIdx.x;
    const int lane = t & 63;
    const int w    = t >> 6;
    const size_t rb = (size_t)blockIdx.x * NN;
    const f32x4* b4 = (const f32x4*)(bi + rb);
    const f32x4* m4 = (const f32x4*)(mk + rb);

    f32x4 pf[8];
    float s = 0.f;
    {
        f32x4 bv[8], mv[8];
#pragma unroll
        for (int kk = 0; kk < 8; ++kk) bv[kk] = __builtin_nontemporal_load(b4 + t + 256 * kk);
#pragma unroll
        for (int kk = 0; kk < 8; ++kk) mv[kk] = __builtin_nontemporal_load(m4 + t + 256 * kk);
#pragma unroll
        for (int kk = 0; kk < 8; ++kk) {
            pf[kk] = bv[kk] * mv[kk];               // nonneg (U[0,1] inputs)
            s += (pf[kk][0] + pf[kk][1]) + (pf[kk][2] + pf[kk][3]);
        }
    }
    // wave reduce
#pragma unroll
    for (int d = 32; d >= 1; d >>= 1) s += __shfl_xor(s, d, 64);
    if (lane == 0) scr[w] = s;
    __syncthreads();
    const float tot   = (scr[0] + scr[1]) + (scr[2] + scr[3]);
    const float scale = 1.0f / fmaxf(tot, 1e-12f);

#pragma unroll
    for (int kk = 0; kk < 8; ++kk) {
        f32x4 o = pf[kk] * scale;                   // normalized
        u16x4 q = { f2bf(o[0]), f2bf(o[1]), f2bf(o[2]), f2bf(o[3]) };
        *((u16x4*)(P + rb) + t + 256 * kk) = q;     // bf16 T, L3-resident
    }
}

// ---------------- K2: T-write + yhat gemm fused ----------------
// 256 blocks x 512 threads (8 waves), 32 rows/block. Wave w: row-group
// rg=w&1, K-quarter kq=w>>1. A-frag loads of P feed BOTH the MFMA and the
// f32 T reconstruction (b2f + nt store) -- T-write rides the gemm's
// latency stalls. Every (row,k) covered exactly once by (rg,kq,lane,k0).
__global__ __launch_bounds__(512)
void lp_gemm(const unsigned short* __restrict__ P, const unsigned short* __restrict__ labT,
             float* __restrict__ T, float* __restrict__ yhat)
{
    __shared__ float scrF[8][16][64];   // 32 KB; index [2*kq+rg]
    const int t    = threadIdx.x;
    const int lane = t & 63;
    const int w    = t >> 6;              // 0..7
    const int rg   = w & 1;               // row-group (16 rows each)
    const int kq   = w >> 1;              // K-quarter (2048)
    const int c15  = lane & 15;
    const int kgrp = (lane >> 4) << 3;
    const int rowbase = blockIdx.x * 32;
    const int kbase   = kq * (NN / 4);
    const int row     = rowbase + rg * 16 + c15;

    const unsigned short* pA  = P + (size_t)row * NN + kbase + kgrp;
    float*                pT  = T + (size_t)row * NN + kbase + kgrp;
    const unsigned short* lb0 = labT + (size_t)(c15)      * NN + kbase + kgrp;
    const unsigned short* lb1 = labT + (size_t)(16 + c15) * NN + kbase + kgrp;
    const unsigned short* lb2 = labT + (size_t)(32 + c15) * NN + kbase + kgrp;
    const unsigned short* lb3 = labT + (size_t)(48 + c15) * NN + kbase + kgrp;

    f32x4 acc0 = {0.f,0.f,0.f,0.f}, acc1 = acc0, acc2 = acc0, acc3 = acc0;
#pragma unroll 4
    for (int k0 = 0; k0 < NN / 4; k0 += 32) {
        short8 a = *(const short8*)(pA + k0);
        // T reconstruction: bf16 -> f32 (shift), nt store (2 x f32x4, 16B aligned)
        f32x4 t0 = { b2f((unsigned short)a[0]), b2f((unsigned short)a[1]),
                     b2f((unsigned short)a[2]), b2f((unsigned short)a[3]) };
        f32x4 t1 = { b2f((unsigned short)a[4]), b2f((unsigned short)a[5]),
                     b2f((unsigned short)a[6]), b2f((unsigned short)a[7]) };
        __builtin_nontemporal_store(t0, (f32x4*)(pT + k0));
        __builtin_nontemporal_store(t1, (f32x4*)(pT + k0 + 4));
        acc0 = __builtin_amdgcn_mfma_f32_16x16x32_bf16(a, *(const short8*)(lb0 + k0), acc0, 0, 0, 0);
        acc1 = __builtin_amdgcn_mfma_f32_16x16x32_bf16(a, *(const short8*)(lb1 + k0), acc1, 0, 0, 0);
        acc2 = __builtin_amdgcn_mfma_f32_16x16x32_bf16(a, *(const short8*)(lb2 + k0), acc2, 0, 0, 0);
        acc3 = __builtin_amdgcn_mfma_f32_16x16x32_bf16(a, *(const short8*)(lb3 + k0), acc3, 0, 0, 0);
    }

    // D layout: col = lane&15, row(within 16) = (lane>>4)*4 + reg
#pragma unroll
    for (int i = 0; i < 4; ++i) {
        const int r15 = (lane >> 4) * 4 + i;
        scrF[w][r15][ 0 + c15] = acc0[i];
        scrF[w][r15][16 + c15] = acc1[i];
        scrF[w][r15][32 + c15] = acc2[i];
        scrF[w][r15][48 + c15] = acc3[i];
    }
    __syncthreads();

    // combine 4 K-quarters per row-group; f32x4 write (32 rows x 64 cols)
    {
        const int o   = t * 4;             // 0 .. 2044
        const int r   = o >> 6;            // 0 .. 31
        const int c0  = o & 63;
        const int g   = r >> 4;            // row-group of this output row
        const int r15 = r & 15;
        f32x4 v = *(const f32x4*)&scrF[g][r15][c0];          // kq=0
#pragma unroll
        for (int q = 1; q < 4; ++q) v += *(const f32x4*)&scrF[2 * q + g][r15][c0];
        *(f32x4*)(yhat + (size_t)(rowbase + r) * CC + c0) = v;
    }
}

// ---------------- fallback: proven fused kernel (round 2) ----------------
__global__ __launch_bounds__(512, 4)
void lp_main_fb(const float* __restrict__ bi, const float* __restrict__ mk,
                const float* __restrict__ labels,
                float* __restrict__ T, float* __restrict__ yhat)
{
    __shared__ unsigned short pT[4 * NN];
    const int t    = threadIdx.x;
    const int lane = t & 63;
    const int w    = t >> 6;
    const size_t rowbase = (size_t)blockIdx.x * 4 * NN;

    float pl[4];
    float h0 = 0.f, h1 = 0.f, h2 = 0.f, h3 = 0.f;
#pragma unroll
    for (int r = 0; r < 4; ++r) {
        const f32x4* b4 = (const f32x4*)(bi + rowbase + (size_t)r * NN);
        const f32x4* m4 = (const f32x4*)(mk + rowbase + (size_t)r * NN);
        float s = 0.f;
#pragma unroll
        for (int k = 0; k < 4; ++k) {
            const int j4 = t + 512 * k;
            f32x4 b = __builtin_nontemporal_load(b4 + j4);
            f32x4 m = __builtin_nontemporal_load(m4 + j4);
            f32x4 p = b * m;
            s += (p[0] + p[1]) + (p[2] + p[3]);
            if (r == 3 && k == 3) { h0 = p[0]; h1 = p[1]; h2 = p[2]; h3 = p[3]; }
            else {
                u16x4 q = { f2bf(p[0]), f2bf(p[1]), f2bf(p[2]), f2bf(p[3]) };
                *(u16x4*)(pT + r * NN + (j4 << 2)) = q;
            }
        }
        pl[r] = s;
    }
#pragma unroll
    for (int r = 0; r < 4; ++r) {
        float s = pl[r];
#pragma unroll
        for (int d = 32; d >= 1; d >>= 1) s += __shfl_xor(s, d, 64);
        pl[r] = s;
    }
    float* scr = (float*)(pT + 3 * NN + 8128);
    if (lane == 0) {
#pragma unroll
        for (int r = 0; r < 4; ++r) scr[w * 4 + r] = pl[r];
    }
    __syncthreads();
    float sc[4];
#pragma unroll
    for (int r = 0; r < 4; ++r) {
        float s = 0.f;
#pragma unroll
        for (int ww = 0; ww < 8; ++ww) s += scr[ww * 4 + r];
        sc[r] = 1.0f / fmaxf(s, 1e-12f);
    }
    __syncthreads();
    {
        const int j4 = t + 1536;
        u16x4 q = { f2bf(h0), f2bf(h1), f2bf(h2), f2bf(h3) };
        *(u16x4*)(pT + 3 * NN + (j4 << 2)) = q;
    }
    __syncthreads();
#pragma unroll
    for (int r = 0; r < 4; ++r) {
        f32x4* To = (f32x4*)(T + rowbase + (size_t)r * NN);
        const float s = sc[r];
#pragma unroll
        for (int k = 0; k < 4; ++k) {
            const int j4 = t + 512 * k;
            u16x4 q = *(const u16x4*)(pT + r * NN + (j4 << 2));
            f32x4 o = { b2f(q[0]) * s, b2f(q[1]) * s, b2f(q[2]) * s, b2f(q[3]) * s };
            __builtin_nontemporal_store(o, To + j4);
        }
    }
    const int c15    = lane & 15;
    const int rowsel = lane & 3;
    const int kgrp   = (lane >> 4) << 3;
    const int kbase  = w * (NN / 8);
    f32x4 acc0 = {0.f,0.f,0.f,0.f}, acc1 = acc0, acc2 = acc0, acc3 = acc0;
    const unsigned short* pA = pT + rowsel * NN + kbase + kgrp;
    for (int k0 = 0; k0 < NN / 8; k0 += 32) {
        short8 a = *(const short8*)(pA + k0);
        short8 q0, q1, q2, q3;
#pragma unroll
        for (int i = 0; i < 8; ++i) {
            const size_t kr = (size_t)(kbase + k0 + kgrp + i) * CC;
            q0[i] = (short)f2bf(labels[kr + c15]);
            q1[i] = (short)f2bf(labels[kr + 16 + c15]);
            q2[i] = (short)f2bf(labels[kr + 32 + c15]);
            q3[i] = (short)f2bf(labels[kr + 48 + c15]);
        }
        acc0 = __builtin_amdgcn_mfma_f32_16x16x32_bf16(a, q0, acc0, 0, 0, 0);
        acc1 = __builtin_amdgcn_mfma_f32_16x16x32_bf16(a, q1, acc1, 0, 0, 0);
        acc2 = __builtin_amdgcn_mfma_f32_16x16x32_bf16(a, q2, acc2, 0, 0, 0);
        acc3 = __builtin_amdgcn_mfma_f32_16x16x32_bf16(a, q3, acc3, 0, 0, 0);
    }
    __syncthreads();
    float* scrF = (float*)pT;
    if (lane < 16) {
#pragma unroll
        for (int i = 0; i < 4; ++i) {
            scrF[((w * 4 + 0) * 4 + i) * 16 + c15] = acc0[i];
            scrF[((w * 4 + 1) * 4 + i) * 16 + c15] = acc1[i];
            scrF[((w * 4 + 2) * 4 + i) * 16 + c15] = acc2[i];
            scrF[((w * 4 + 3) * 4 + i) * 16 + c15] = acc3[i];
        }
    }
    __syncthreads();
    if (t < 256) {
        const int r  = t >> 6;
        const int c  = t & 63;
        const int j  = c >> 4;
        const int cl = c & 15;
        float s = 0.f;
#pragma unroll
        for (int ww = 0; ww < 8; ++ww)
            s += scrF[((ww * 4 + j) * 4 + r) * 16 + cl];
        const float scl = (r == 0) ? sc[0] : (r == 1) ? sc[1] : (r == 2) ? sc[2] : sc[3];
        yhat[(size_t)blockIdx.x * 4 * CC + (size_t)r * CC + c] = s * scl;
    }
}

extern "C" void kernel_launch(void* const* d_in, const int* in_sizes, int n_in,
                              void* d_out, int out_size, void* d_ws, size_t ws_size,
                              hipStream_t stream) {
    (void)in_sizes; (void)n_in; (void)out_size;
    const float* labels = (const float*)d_in[2];
    const float* bi     = (const float*)d_in[4];
    const float* mask   = (const float*)d_in[5];
    float* T    = (float*)d_out;
    float* yhat = (float*)d_out + (size_t)NN * NN;

    const size_t labT_bytes = (size_t)NN * CC * 2;          // 1 MB
    const size_t P_bytes    = (size_t)NN * NN * 2;          // 128 MB

    if (ws_size >= labT_bytes + P_bytes) {
        unsigned short* labT = (unsigned short*)d_ws;
        unsigned short* P    = (unsigned short*)((char*)d_ws + labT_bytes);
        prep_labels<<<dim3(NN * CC / 4 / 256), dim3(256), 0, stream>>>(labels, labT);
        lp_stream<<<dim3(NN), dim3(256), 0, stream>>>(bi, mask, P);
        lp_gemm<<<dim3(NN / 32), dim3(512), 0, stream>>>(P, labT, T, yhat);
    } else {
        lp_main_fb<<<dim3(NN / 4), dim3(512), 0, stream>>>(bi, mask, labels, T, yhat);
    }
}

// Round 13
// 244.014 us; speedup vs baseline: 1.2059x; 1.2059x over previous
//
#include <hip/hip_runtime.h>

#define NN 8192
#define CC 64

typedef float f32x4 __attribute__((ext_vector_type(4)));
typedef short short8 __attribute__((ext_vector_type(8)));
typedef unsigned short u16x4 __attribute__((ext_vector_type(4)));

__device__ __forceinline__ unsigned short f2bf(float f) {
    union { float f; unsigned u; } v; v.f = f;
    return (unsigned short)((v.u + 0x7fffu + ((v.u >> 16) & 1u)) >> 16);
}
__device__ __forceinline__ float b2f(unsigned short h) {
    union { unsigned u; float f; } v; v.u = ((unsigned)h) << 16;
    return v.f;
}

// labT[c][k] = bf16(labels[k][c]); grid 512 x 256
__global__ __launch_bounds__(256)
void prep_labels(const float* __restrict__ labels, unsigned short* __restrict__ labT) {
    const int gid = blockIdx.x * 256 + threadIdx.x;   // 0 .. 131071
    const int k  = gid >> 4;
    const int c4 = (gid & 15) << 2;
    f32x4 v = *(const f32x4*)(labels + (size_t)k * CC + c4);
#pragma unroll
    for (int j = 0; j < 4; ++j)
        labT[(size_t)(c4 + j) * NN + k] = f2bf(v[j]);
}

// ---------------- K1: streaming normalize -> P only (r12 verbatim, ~99us) --
// One row per 256-thread block. Read b,m (nt); f32 products in regs;
// row L1 sum; P = bf16(p*scale) (plain store -> L3 for K2). NO T store.
__global__ __launch_bounds__(256)
void lp_stream(const float* __restrict__ bi, const float* __restrict__ mk,
               unsigned short* __restrict__ P)
{
    __shared__ float scr[4];
    const int t    = threadIdx.x;
    const int lane = t & 63;
    const int w    = t >> 6;
    const size_t rb = (size_t)blockIdx.x * NN;
    const f32x4* b4 = (const f32x4*)(bi + rb);
    const f32x4* m4 = (const f32x4*)(mk + rb);

    f32x4 pf[8];
    float s = 0.f;
    {
        f32x4 bv[8], mv[8];
#pragma unroll
        for (int kk = 0; kk < 8; ++kk) bv[kk] = __builtin_nontemporal_load(b4 + t + 256 * kk);
#pragma unroll
        for (int kk = 0; kk < 8; ++kk) mv[kk] = __builtin_nontemporal_load(m4 + t + 256 * kk);
#pragma unroll
        for (int kk = 0; kk < 8; ++kk) {
            pf[kk] = bv[kk] * mv[kk];               // nonneg (U[0,1] inputs)
            s += (pf[kk][0] + pf[kk][1]) + (pf[kk][2] + pf[kk][3]);
        }
    }
    // wave reduce
#pragma unroll
    for (int d = 32; d >= 1; d >>= 1) s += __shfl_xor(s, d, 64);
    if (lane == 0) scr[w] = s;
    __syncthreads();
    const float tot   = (scr[0] + scr[1]) + (scr[2] + scr[3]);
    const float scale = 1.0f / fmaxf(tot, 1e-12f);

#pragma unroll
    for (int kk = 0; kk < 8; ++kk) {
        f32x4 o = pf[kk] * scale;                   // normalized
        u16x4 q = { f2bf(o[0]), f2bf(o[1]), f2bf(o[2]), f2bf(o[3]) };
        *((u16x4*)(P + rb) + t + 256 * kk) = q;     // bf16 T, L3-resident
    }
}

// ---------------- K2 v3: contiguous T-write + yhat gemm ----------------
// 256 blocks x 512 threads (8 waves), 32 rows/block.
// Phase A: T = f32(P) with LANE-CONTIGUOUS nt stores (1 KB/instr — no
//          partial-line amplification; r12's fragment-layout nt stores
//          cost 1.53x write traffic).
// Phase B: MFMA gemm (r11 layout). Stores drain under MFMA latency.
__global__ __launch_bounds__(512)
void lp_gemm(const unsigned short* __restrict__ P, const unsigned short* __restrict__ labT,
             float* __restrict__ T, float* __restrict__ yhat)
{
    __shared__ float scrF[8][16][64];   // 32 KB; index [2*kq+rg]
    const int t    = threadIdx.x;
    const size_t base = (size_t)blockIdx.x * 32 * NN;   // 32 rows

    // ---- phase A: contiguous T reconstruction ----
    {
        const u16x4* Pin  = (const u16x4*)(P + base);
        f32x4*       Tout = (f32x4*)(T + base);
#pragma unroll 8
        for (int i = 0; i < (32 * NN / 4) / 512; ++i) {   // 128 iters
            u16x4 q = Pin[t + 512 * i];
            f32x4 o = { b2f(q[0]), b2f(q[1]), b2f(q[2]), b2f(q[3]) };
            __builtin_nontemporal_store(o, Tout + t + 512 * i);
        }
    }

    // ---- phase B: MFMA gemm (r11 verbatim) ----
    const int lane = t & 63;
    const int w    = t >> 6;              // 0..7
    const int rg   = w & 1;               // row-group (16 rows each)
    const int kq   = w >> 1;              // K-quarter (2048)
    const int c15  = lane & 15;
    const int kgrp = (lane >> 4) << 3;
    const int rowbase = blockIdx.x * 32;
    const int kbase   = kq * (NN / 4);

    const unsigned short* pA  = P + (size_t)(rowbase + rg * 16 + c15) * NN + kbase + kgrp;
    const unsigned short* lb0 = labT + (size_t)(c15)      * NN + kbase + kgrp;
    const unsigned short* lb1 = labT + (size_t)(16 + c15) * NN + kbase + kgrp;
    const unsigned short* lb2 = labT + (size_t)(32 + c15) * NN + kbase + kgrp;
    const unsigned short* lb3 = labT + (size_t)(48 + c15) * NN + kbase + kgrp;

    f32x4 acc0 = {0.f,0.f,0.f,0.f}, acc1 = acc0, acc2 = acc0, acc3 = acc0;
#pragma unroll 4
    for (int k0 = 0; k0 < NN / 4; k0 += 32) {
        short8 a = *(const short8*)(pA + k0);
        acc0 = __builtin_amdgcn_mfma_f32_16x16x32_bf16(a, *(const short8*)(lb0 + k0), acc0, 0, 0, 0);
        acc1 = __builtin_amdgcn_mfma_f32_16x16x32_bf16(a, *(const short8*)(lb1 + k0), acc1, 0, 0, 0);
        acc2 = __builtin_amdgcn_mfma_f32_16x16x32_bf16(a, *(const short8*)(lb2 + k0), acc2, 0, 0, 0);
        acc3 = __builtin_amdgcn_mfma_f32_16x16x32_bf16(a, *(const short8*)(lb3 + k0), acc3, 0, 0, 0);
    }

    // D layout: col = lane&15, row(within 16) = (lane>>4)*4 + reg
#pragma unroll
    for (int i = 0; i < 4; ++i) {
        const int r15 = (lane >> 4) * 4 + i;
        scrF[w][r15][ 0 + c15] = acc0[i];
        scrF[w][r15][16 + c15] = acc1[i];
        scrF[w][r15][32 + c15] = acc2[i];
        scrF[w][r15][48 + c15] = acc3[i];
    }
    __syncthreads();

    // combine 4 K-quarters per row-group; f32x4 write (32 rows x 64 cols)
    {
        const int o   = t * 4;             // 0 .. 2044
        const int r   = o >> 6;            // 0 .. 31
        const int c0  = o & 63;
        const int g   = r >> 4;            // row-group of this output row
        const int r15 = r & 15;
        f32x4 v = *(const f32x4*)&scrF[g][r15][c0];          // kq=0
#pragma unroll
        for (int q = 1; q < 4; ++q) v += *(const f32x4*)&scrF[2 * q + g][r15][c0];
        *(f32x4*)(yhat + (size_t)(rowbase + r) * CC + c0) = v;
    }
}

// ---------------- fallback: proven fused kernel (round 2) ----------------
__global__ __launch_bounds__(512, 4)
void lp_main_fb(const float* __restrict__ bi, const float* __restrict__ mk,
                const float* __restrict__ labels,
                float* __restrict__ T, float* __restrict__ yhat)
{
    __shared__ unsigned short pT[4 * NN];
    const int t    = threadIdx.x;
    const int lane = t & 63;
    const int w    = t >> 6;
    const size_t rowbase = (size_t)blockIdx.x * 4 * NN;

    float pl[4];
    float h0 = 0.f, h1 = 0.f, h2 = 0.f, h3 = 0.f;
#pragma unroll
    for (int r = 0; r < 4; ++r) {
        const f32x4* b4 = (const f32x4*)(bi + rowbase + (size_t)r * NN);
        const f32x4* m4 = (const f32x4*)(mk + rowbase + (size_t)r * NN);
        float s = 0.f;
#pragma unroll
        for (int k = 0; k < 4; ++k) {
            const int j4 = t + 512 * k;
            f32x4 b = __builtin_nontemporal_load(b4 + j4);
            f32x4 m = __builtin_nontemporal_load(m4 + j4);
            f32x4 p = b * m;
            s += (p[0] + p[1]) + (p[2] + p[3]);
            if (r == 3 && k == 3) { h0 = p[0]; h1 = p[1]; h2 = p[2]; h3 = p[3]; }
            else {
                u16x4 q = { f2bf(p[0]), f2bf(p[1]), f2bf(p[2]), f2bf(p[3]) };
                *(u16x4*)(pT + r * NN + (j4 << 2)) = q;
            }
        }
        pl[r] = s;
    }
#pragma unroll
    for (int r = 0; r < 4; ++r) {
        float s = pl[r];
#pragma unroll
        for (int d = 32; d >= 1; d >>= 1) s += __shfl_xor(s, d, 64);
        pl[r] = s;
    }
    float* scr = (float*)(pT + 3 * NN + 8128);
    if (lane == 0) {
#pragma unroll
        for (int r = 0; r < 4; ++r) scr[w * 4 + r] = pl[r];
    }
    __syncthreads();
    float sc[4];
#pragma unroll
    for (int r = 0; r < 4; ++r) {
        float s = 0.f;
#pragma unroll
        for (int ww = 0; ww < 8; ++ww) s += scr[ww * 4 + r];
        sc[r] = 1.0f / fmaxf(s, 1e-12f);
    }
    __syncthreads();
    {
        const int j4 = t + 1536;
        u16x4 q = { f2bf(h0), f2bf(h1), f2bf(h2), f2bf(h3) };
        *(u16x4*)(pT + 3 * NN + (j4 << 2)) = q;
    }
    __syncthreads();
#pragma unroll
    for (int r = 0; r < 4; ++r) {
        f32x4* To = (f32x4*)(T + rowbase + (size_t)r * NN);
        const float s = sc[r];
#pragma unroll
        for (int k = 0; k < 4; ++k) {
            const int j4 = t + 512 * k;
            u16x4 q = *(const u16x4*)(pT + r * NN + (j4 << 2));
            f32x4 o = { b2f(q[0]) * s, b2f(q[1]) * s, b2f(q[2]) * s, b2f(q[3]) * s };
            __builtin_nontemporal_store(o, To + j4);
        }
    }
    const int c15    = lane & 15;
    const int rowsel = lane & 3;
    const int kgrp   = (lane >> 4) << 3;
    const int kbase  = w * (NN / 8);
    f32x4 acc0 = {0.f,0.f,0.f,0.f}, acc1 = acc0, acc2 = acc0, acc3 = acc0;
    const unsigned short* pA = pT + rowsel * NN + kbase + kgrp;
    for (int k0 = 0; k0 < NN / 8; k0 += 32) {
        short8 a = *(const short8*)(pA + k0);
        short8 q0, q1, q2, q3;
#pragma unroll
        for (int i = 0; i < 8; ++i) {
            const size_t kr = (size_t)(kbase + k0 + kgrp + i) * CC;
            q0[i] = (short)f2bf(labels[kr + c15]);
            q1[i] = (short)f2bf(labels[kr + 16 + c15]);
            q2[i] = (short)f2bf(labels[kr + 32 + c15]);
            q3[i] = (short)f2bf(labels[kr + 48 + c15]);
        }
        acc0 = __builtin_amdgcn_mfma_f32_16x16x32_bf16(a, q0, acc0, 0, 0, 0);
        acc1 = __builtin_amdgcn_mfma_f32_16x16x32_bf16(a, q1, acc1, 0, 0, 0);
        acc2 = __builtin_amdgcn_mfma_f32_16x16x32_bf16(a, q2, acc2, 0, 0, 0);
        acc3 = __builtin_amdgcn_mfma_f32_16x16x32_bf16(a, q3, acc3, 0, 0, 0);
    }
    __syncthreads();
    float* scrF = (float*)pT;
    if (lane < 16) {
#pragma unroll
        for (int i = 0; i < 4; ++i) {
            scrF[((w * 4 + 0) * 4 + i) * 16 + c15] = acc0[i];
            scrF[((w * 4 + 1) * 4 + i) * 16 + c15] = acc1[i];
            scrF[((w * 4 + 2) * 4 + i) * 16 + c15] = acc2[i];
            scrF[((w * 4 + 3) * 4 + i) * 16 + c15] = acc3[i];
        }
    }
    __syncthreads();
    if (t < 256) {
        const int r  = t >> 6;
        const int c  = t & 63;
        const int j  = c >> 4;
        const int cl = c & 15;
        float s = 0.f;
#pragma unroll
        for (int ww = 0; ww < 8; ++ww)
            s += scrF[((ww * 4 + j) * 4 + r) * 16 + cl];
        const float scl = (r == 0) ? sc[0] : (r == 1) ? sc[1] : (r == 2) ? sc[2] : sc[3];
        yhat[(size_t)blockIdx.x * 4 * CC + (size_t)r * CC + c] = s * scl;
    }
}

extern "C" void kernel_launch(void* const* d_in, const int* in_sizes, int n_in,
                              void* d_out, int out_size, void* d_ws, size_t ws_size,
                              hipStream_t stream) {
    (void)in_sizes; (void)n_in; (void)out_size;
    const float* labels = (const float*)d_in[2];
    const float* bi     = (const float*)d_in[4];
    const float* mask   = (const float*)d_in[5];
    float* T    = (float*)d_out;
    float* yhat = (float*)d_out + (size_t)NN * NN;

    const size_t labT_bytes = (size_t)NN * CC * 2;          // 1 MB
    const size_t P_bytes    = (size_t)NN * NN * 2;          // 128 MB

    if (ws_size >= labT_bytes + P_bytes) {
        unsigned short* labT = (unsigned short*)d_ws;
        unsigned short* P    = (unsigned short*)((char*)d_ws + labT_bytes);
        prep_labels<<<dim3(NN * CC / 4 / 256), dim3(256), 0, stream>>>(labels, labT);
        lp_stream<<<dim3(NN), dim3(256), 0, stream>>>(bi, mask, P);
        lp_gemm<<<dim3(NN / 32), dim3(512), 0, stream>>>(P, labT, T, yhat);
    } else {
        lp_main_fb<<<dim3(NN / 4), dim3(512), 0, stream>>>(bi, mask, labels, T, yhat);
    }
}